// Round 14
// baseline (62.236 us; speedup 1.0000x reference)
//
#include <hip/hip_runtime.h>
#include <math.h>

#define HH  128   // hidden size
#define SS  1000  // sequence length
#define NSH 500   // s per half-batch block
#define NT  1024
#define C1 2.8853900817779268f  // 2*log2(e)
#define C2 1.4426950408889634f  // log2(e)

typedef float v2f __attribute__((ext_vector_type(2)));

// DPP adds: row_shr within 16-lane rows; row_bcast15 completes 32-lane sums
// at lanes 31/63. Verified absmax-0 (R8/R10/R11/R13).
template <int CTRL>
__device__ __forceinline__ float dpp_add(float x) {
    int s = __builtin_amdgcn_update_dpp(0, __builtin_bit_cast(int, x),
                                        CTRL, 0xF, 0xF, true);
    return x + __builtin_bit_cast(float, s);
}

// ws float layout:
//   [0..1024)  kc rows 0..7 (row*128+h):
//     0:a0*C1 1:a1*C1 2:ad*C1 3:v 4:cc*C1 5:(cc+w3b)*C1 6:w30*C1 7:w31*C1
//   [1024]     svc2 = sum(v)*log2(e)
//   [1088 + ((iter*B + b)*2 + half)*4)  partial {S,Sx0,Sx1,0}   (< 7232)
//   [7232..7744) as int: flags[512]  (zeroed by sc_fold each call)
#define WS_PART 1088
#define WS_FLAG 7232

// ---- fold kernel: grid 4 x 1024 (verified R10/R11/R13) + flag zeroing ----
__global__ __launch_bounds__(NT) void sc_fold(
    const float* __restrict__ enc_s_w, const float* __restrict__ enc_s_b,
    const float* __restrict__ enc_d_w, const float* __restrict__ enc_d_b,
    const float* __restrict__ v, const float* __restrict__ W,
    float* __restrict__ ws) {
    const int t  = threadIdx.x;
    const int fh = blockIdx.x * 32 + (t >> 5);
    const int fq = t & 31;
    const float4* W1 = (const float4*)(W + fh * (3 * HH));
    const float4* W2 = (const float4*)(W + fh * (3 * HH) + HH);
    const float4* W3 = (const float4*)(W + fh * (3 * HH) + 2 * HH);
    const float4* ES = (const float4*)enc_s_w;
    const float4* ED = (const float4*)enc_d_w;
    const float4* SB = (const float4*)enc_s_b;
    const float4* DB = (const float4*)enc_d_b;
    const int k4 = fq;
    float4 w1 = W1[k4], w2 = W2[k4], w3 = W3[k4];
    float4 e01 = ES[2 * k4], e23 = ES[2 * k4 + 1];
    float4 d01 = ED[2 * k4], d23 = ED[2 * k4 + 1];
    float4 sb = SB[k4], db = DB[k4];
    float a0 = 0.f, a1 = 0.f, ad = 0.f, cc = 0.f, w30 = 0.f, w31 = 0.f, w3b = 0.f;
    a0 = fmaf(w1.x, e01.x, a0); a0 = fmaf(w1.y, e01.z, a0);
    a0 = fmaf(w1.z, e23.x, a0); a0 = fmaf(w1.w, e23.z, a0);
    a1 = fmaf(w1.x, e01.y, a1); a1 = fmaf(w1.y, e01.w, a1);
    a1 = fmaf(w1.z, e23.y, a1); a1 = fmaf(w1.w, e23.w, a1);
    ad = fmaf(w2.x, d01.x + d01.y, ad); ad = fmaf(w2.y, d01.z + d01.w, ad);
    ad = fmaf(w2.z, d23.x + d23.y, ad); ad = fmaf(w2.w, d23.z + d23.w, ad);
    cc = fmaf(w1.x, sb.x, cc); cc = fmaf(w1.y, sb.y, cc);
    cc = fmaf(w1.z, sb.z, cc); cc = fmaf(w1.w, sb.w, cc);
    cc = fmaf(w2.x, db.x, cc); cc = fmaf(w2.y, db.y, cc);
    cc = fmaf(w2.z, db.z, cc); cc = fmaf(w2.w, db.w, cc);
    w30 = fmaf(w3.x, e01.x, w30); w30 = fmaf(w3.y, e01.z, w30);
    w30 = fmaf(w3.z, e23.x, w30); w30 = fmaf(w3.w, e23.z, w30);
    w31 = fmaf(w3.x, e01.y, w31); w31 = fmaf(w3.y, e01.w, w31);
    w31 = fmaf(w3.z, e23.y, w31); w31 = fmaf(w3.w, e23.w, w31);
    w3b = fmaf(w3.x, sb.x, w3b); w3b = fmaf(w3.y, sb.y, w3b);
    w3b = fmaf(w3.z, sb.z, w3b); w3b = fmaf(w3.w, sb.w, w3b);
    a0  = dpp_add<0x111>(a0);  a0  = dpp_add<0x112>(a0);  a0  = dpp_add<0x114>(a0);
    a0  = dpp_add<0x118>(a0);  a0  = dpp_add<0x142>(a0);
    a1  = dpp_add<0x111>(a1);  a1  = dpp_add<0x112>(a1);  a1  = dpp_add<0x114>(a1);
    a1  = dpp_add<0x118>(a1);  a1  = dpp_add<0x142>(a1);
    ad  = dpp_add<0x111>(ad);  ad  = dpp_add<0x112>(ad);  ad  = dpp_add<0x114>(ad);
    ad  = dpp_add<0x118>(ad);  ad  = dpp_add<0x142>(ad);
    cc  = dpp_add<0x111>(cc);  cc  = dpp_add<0x112>(cc);  cc  = dpp_add<0x114>(cc);
    cc  = dpp_add<0x118>(cc);  cc  = dpp_add<0x142>(cc);
    w30 = dpp_add<0x111>(w30); w30 = dpp_add<0x112>(w30); w30 = dpp_add<0x114>(w30);
    w30 = dpp_add<0x118>(w30); w30 = dpp_add<0x142>(w30);
    w31 = dpp_add<0x111>(w31); w31 = dpp_add<0x112>(w31); w31 = dpp_add<0x114>(w31);
    w31 = dpp_add<0x118>(w31); w31 = dpp_add<0x142>(w31);
    w3b = dpp_add<0x111>(w3b); w3b = dpp_add<0x112>(w3b); w3b = dpp_add<0x114>(w3b);
    w3b = dpp_add<0x118>(w3b); w3b = dpp_add<0x142>(w3b);
    if (fq == 31) {
        ws[0 * HH + fh] = a0 * C1;
        ws[1 * HH + fh] = a1 * C1;
        ws[2 * HH + fh] = ad * C1;
        ws[4 * HH + fh] = cc * C1;
        ws[5 * HH + fh] = (cc + w3b) * C1;
        ws[6 * HH + fh] = w30 * C1;
        ws[7 * HH + fh] = w31 * C1;
    }
    if (blockIdx.x == 0) {
        if (t < HH) ws[3 * HH + t] = v[t];
        if (t < 32) {
            float4 x = ((const float4*)v)[t];
            float s = (x.x + x.y) + (x.z + x.w);
            #pragma unroll
            for (int off = 1; off < 32; off <<= 1) s += __shfl_xor(s, off);
            if (t == 0) ws[8 * HH] = s * C2;
        }
        if (t < 512) ((int*)(ws + WS_FLAG))[t] = 0;  // handshake flags
    }
}

// ---- main kernel: grid 2B x 1024, REGULAR launch. 2 blocks/CU (8 w/SIMD).
// Co-residency: 512 blocks == 256 CU x 2-block capacity (VGPR<=64 via
// launch_bounds, LDS ~9KB). Pairwise release/acquire handshake per iter.
__global__ __launch_bounds__(NT, 8) void sc_coop(
    const float* __restrict__ stat, const float* __restrict__ dyn,
    float* __restrict__ ws,
    const float* __restrict__ enc_s_w, const float* __restrict__ enc_s_b,
    const float* __restrict__ dense_w, const float* __restrict__ dense_b,
    const float* __restrict__ lin_w, const float* __restrict__ lin_b,
    float* __restrict__ out, int B) {
    const int bid  = blockIdx.x;
    const int b    = bid >> 1;
    const int half = bid & 1;
    const int t    = threadIdx.x;
    const int lane = t & 63;
    const int g    = t & 31;   // h-slice: h = 4g .. 4g+3
    const int sg   = t >> 5;   // s-slot 0..31; s_local = pass*32 + sg

    __shared__ __align__(16) float4 xs[512];
    __shared__ float4 red4[NT / 64];
    __shared__ float bc[2];
    __shared__ float hy_sh[HH];

    int* flags = (int*)(ws + WS_FLAG);

    // stage this half's inputs
    if (t < 512) {
        float x0 = 0.f, x1 = 0.f, yv = 0.f;
        if (t < NSH) {
            const int s = half * NSH + t;
            const float* sbp = stat + (size_t)b * 2 * SS;
            x0 = sbp[s];
            x1 = sbp[SS + s];
            yv = dyn[(size_t)b * 2 * SS + SS + s];
        }
        xs[t] = make_float4(x0, x1, yv, 0.f);
    }

    // per-lane register constants (4 h each) — R8-proven <=32 VGPR core
    const int h4 = g * 4;
    float4 u;
    u = *(const float4*)(ws + 0 * HH + h4); const v2f a0_0 = {u.x, u.y}, a0_1 = {u.z, u.w};
    u = *(const float4*)(ws + 1 * HH + h4); const v2f a1_0 = {u.x, u.y}, a1_1 = {u.z, u.w};
    u = *(const float4*)(ws + 2 * HH + h4); const v2f ad_0 = {u.x, u.y}, ad_1 = {u.z, u.w};
    u = *(const float4*)(ws + 3 * HH + h4); const v2f vv_0 = {u.x, u.y}, vv_1 = {u.z, u.w};
    const float c01 = vv_0.x + vv_0.y;
    const float c23 = vv_1.x + vv_1.y;
    const float svc2 = ws[8 * HH];
    const v2f clampv = {24.f, 24.f};
    const bool owner = (g == 31);

    __syncthreads();  // xs ready

    float X0 = 0.f, X1 = 0.f;

    for (int iter = 0; iter < 3; ++iter) {
        v2f cg_0, cg_1;
        if (iter == 0) {
            u = *(const float4*)(ws + 4 * HH + h4);
            cg_0 = (v2f){u.x, u.y};
            cg_1 = (v2f){u.z, u.w};
        } else {
            float4 ub = *(const float4*)(ws + 5 * HH + h4);
            float4 u0 = *(const float4*)(ws + 6 * HH + h4);
            float4 u1 = *(const float4*)(ws + 7 * HH + h4);
            v2f X0v = {X0, X0}, X1v = {X1, X1};
            cg_0 = __builtin_elementwise_fma(
                (v2f){u0.x, u0.y}, X0v,
                __builtin_elementwise_fma((v2f){u1.x, u1.y}, X1v, (v2f){ub.x, ub.y}));
            cg_1 = __builtin_elementwise_fma(
                (v2f){u0.z, u0.w}, X0v,
                __builtin_elementwise_fma((v2f){u1.z, u1.w}, X1v, (v2f){ub.z, ub.w}));
        }

        float S = 0.f, Sx0 = 0.f, Sx1 = 0.f;
        #pragma unroll 4
        for (int pass = 0; pass < 16; ++pass) {
            const int sl = pass * 32 + sg;
            float4 x = xs[sl];
            v2f vx0 = {x.x, x.x}, vx1 = {x.y, x.y}, vyv = {x.z, x.z};
            v2f z0 = __builtin_elementwise_fma(
                a0_0, vx0, __builtin_elementwise_fma(
                    a1_0, vx1, __builtin_elementwise_fma(ad_0, vyv, cg_0)));
            v2f z1 = __builtin_elementwise_fma(
                a0_1, vx0, __builtin_elementwise_fma(
                    a1_1, vx1, __builtin_elementwise_fma(ad_1, vyv, cg_1)));
            z0 = __builtin_elementwise_min(z0, clampv);
            z1 = __builtin_elementwise_min(z1, clampv);
            float e0 = __builtin_amdgcn_exp2f(z0.x);
            float e1 = __builtin_amdgcn_exp2f(z0.y);
            float e2 = __builtin_amdgcn_exp2f(z1.x);
            float e3 = __builtin_amdgcn_exp2f(z1.y);
            // 4 sigmoids, one rcp (verified R9/R10)
            float t1  = 1.f + e1, t3 = 1.f + e3;
            float d01 = fmaf(e0, t1, t1);
            float d23 = fmaf(e2, t3, t3);
            float n01 = fmaf(vv_0.x, e1, fmaf(vv_0.y, e0, c01));
            float n23 = fmaf(vv_1.x, e3, fmaf(vv_1.y, e2, c23));
            float num = fmaf(n01, d23, n23 * d01);
            float acc = num * __builtin_amdgcn_rcpf(d01 * d23);
            acc = dpp_add<0x111>(acc);
            acc = dpp_add<0x112>(acc);
            acc = dpp_add<0x114>(acc);
            acc = dpp_add<0x118>(acc);
            acc = dpp_add<0x142>(acc);
            const bool own = owner && (sl < NSH);
            float arg = own ? fmaf(-C1, acc, svc2) : -200.f;
            float pe = __builtin_amdgcn_exp2f(arg);
            S   += pe;
            Sx0  = fmaf(pe, x.x, Sx0);
            Sx1  = fmaf(pe, x.y, Sx1);
        }
        S   += __shfl_xor(S, 32);
        Sx0 += __shfl_xor(Sx0, 32);
        Sx1 += __shfl_xor(Sx1, 32);
        if (lane == 31) red4[t >> 6] = make_float4(S, Sx0, Sx1, 0.f);
        __syncthreads();
        float4 w4 = red4[lane & 15];
        #pragma unroll
        for (int off = 1; off < 16; off <<= 1) {
            w4.x += __shfl_xor(w4.x, off);
            w4.y += __shfl_xor(w4.y, off);
            w4.z += __shfl_xor(w4.z, off);
        }
        // pairwise handshake: publish own partial, await partner's
        if (t == 0) {
            float* mine = ws + WS_PART + ((iter * B + b) * 2 + half) * 4;
            mine[0] = w4.x; mine[1] = w4.y; mine[2] = w4.z;
            __hip_atomic_store(&flags[bid], iter + 1, __ATOMIC_RELEASE,
                               __HIP_MEMORY_SCOPE_AGENT);
            while (__hip_atomic_load(&flags[bid ^ 1], __ATOMIC_ACQUIRE,
                                     __HIP_MEMORY_SCOPE_AGENT) < iter + 1)
                __builtin_amdgcn_s_sleep(2);
            const float* po = ws + WS_PART + ((iter * B + b) * 2 + (half ^ 1)) * 4;
            float pS  = __hip_atomic_load(po + 0, __ATOMIC_RELAXED,
                                          __HIP_MEMORY_SCOPE_AGENT);
            float pX0 = __hip_atomic_load(po + 1, __ATOMIC_RELAXED,
                                          __HIP_MEMORY_SCOPE_AGENT);
            float pX1 = __hip_atomic_load(po + 2, __ATOMIC_RELAXED,
                                          __HIP_MEMORY_SCOPE_AGENT);
            // fixed combine order (half0 + half1) -> identical in both blocks
            float s0 = half ? pS  : w4.x,  s1 = half ? w4.x : pS;
            float a0v = half ? pX0 : w4.y, a1v = half ? w4.y : pX0;
            float b0v = half ? pX1 : w4.z, b1v = half ? w4.z : pX1;
            float inv = __builtin_amdgcn_rcpf(s0 + s1);
            bc[0] = (a0v + a1v) * inv;
            bc[1] = (b0v + b1v) * inv;
        }
        __syncthreads();
        X0 = bc[0];
        X1 = bc[1];
    }

    // epilogue: half 0 only
    if (half == 0) {
        if (t < HH)
            hy_sh[t] = fmaf(enc_s_w[2 * t], X0, fmaf(enc_s_w[2 * t + 1], X1, enc_s_b[t]));
        __syncthreads();
        float o = 0.f;
        if (t < HH) {
            const float4* dw4 = (const float4*)(dense_w + t * HH);
            const float4* hy4 = (const float4*)hy_sh;
            float r = dense_b[t];
            #pragma unroll 4
            for (int k = 0; k < HH / 4; ++k) {
                float4 d4 = dw4[k], h4v = hy4[k];
                r = fmaf(d4.x, h4v.x, fmaf(d4.y, h4v.y,
                        fmaf(d4.z, h4v.z, fmaf(d4.w, h4v.w, r))));
            }
            o = lin_w[t] * fmaxf(r, 0.f);
        }
        #pragma unroll
        for (int off = 32; off > 0; off >>= 1) o += __shfl_xor(o, off);
        if (lane == 0) red4[t >> 6].x = o;
        __syncthreads();
        if (t == 0) out[b] = red4[0].x + red4[1].x + lin_b[0];
    }
}

extern "C" void kernel_launch(void* const* d_in, const int* in_sizes, int n_in,
                              void* d_out, int out_size, void* d_ws, size_t ws_size,
                              hipStream_t stream) {
    const float* stat    = (const float*)d_in[0];
    const float* dyn     = (const float*)d_in[1];
    const float* enc_s_w = (const float*)d_in[2];
    const float* enc_s_b = (const float*)d_in[3];
    const float* enc_d_w = (const float*)d_in[4];
    const float* enc_d_b = (const float*)d_in[5];
    const float* v       = (const float*)d_in[6];
    const float* W       = (const float*)d_in[7];
    const float* dense_w = (const float*)d_in[8];
    const float* dense_b = (const float*)d_in[9];
    const float* lin_w   = (const float*)d_in[10];
    const float* lin_b   = (const float*)d_in[11];
    float* out = (float*)d_out;
    float* ws  = (float*)d_ws;

    int B = in_sizes[0] / (2 * SS);

    hipLaunchKernelGGL(sc_fold, dim3(4), dim3(NT), 0, stream,
                       enc_s_w, enc_s_b, enc_d_w, enc_d_b, v, W, ws);
    hipLaunchKernelGGL(sc_coop, dim3(2 * B), dim3(NT), 0, stream,
                       stat, dyn, ws, enc_s_w, enc_s_b, dense_w, dense_b,
                       lin_w, lin_b, out, B);
}

// Round 15
// 52.267 us; speedup vs baseline: 1.1907x; 1.1907x over previous
//
#include <hip/hip_runtime.h>
#include <math.h>

#define HH  128   // hidden size
#define SS  1000  // sequence length
#define NT  1024  // threads per block (16 waves)
#define NW  (NT / 64)
#define C2 1.4426950408889634f  // log2(e)

// normalized Pade[7/8] tanh coefficients: tanh(z) ~ z*P'(t)/Q'(t), t=z^2
// P' = 1 + t(PA1 + t(PA2 + t*PA3)), Q' = 1 + t(QB1 + t(QB2 + t*QB3))
#define PA1 0.12820513f
#define PA2 2.7972028e-3f
#define PA3 7.3998593e-6f
#define QB1 0.46153846f
#define QB2 0.023310023f
#define QB3 2.0720021e-4f

typedef float v2f __attribute__((ext_vector_type(2)));

// DPP adds: row_shr:N suffix-sums within 16-lane rows toward lane 15.
// Verified absmax-0 in R8/R10/R11/R13.
template <int CTRL>
__device__ __forceinline__ float dpp_add(float x) {
    int s = __builtin_amdgcn_update_dpp(0, __builtin_bit_cast(int, x),
                                        CTRL, 0xF, 0xF, true);
    return x + __builtin_bit_cast(float, s);
}

// ws float layout: [0..1024) kc rows 0..7 (row*128+h), ALL UNSCALED now:
//   0:a0 1:a1 2:ad 3:v 4:cc 5:(cc+w3b) 6:w30 7:w31

// ---- fold kernel: grid 4 x 1024 (R10-verified, C1 scaling removed) ----
__global__ __launch_bounds__(NT) void sc_fold(
    const float* __restrict__ enc_s_w, const float* __restrict__ enc_s_b,
    const float* __restrict__ enc_d_w, const float* __restrict__ enc_d_b,
    const float* __restrict__ v, const float* __restrict__ W,
    float* __restrict__ ws) {
    const int t  = threadIdx.x;
    const int fh = blockIdx.x * 32 + (t >> 5);
    const int fq = t & 31;
    const float4* W1 = (const float4*)(W + fh * (3 * HH));
    const float4* W2 = (const float4*)(W + fh * (3 * HH) + HH);
    const float4* W3 = (const float4*)(W + fh * (3 * HH) + 2 * HH);
    const float4* ES = (const float4*)enc_s_w;
    const float4* ED = (const float4*)enc_d_w;
    const float4* SB = (const float4*)enc_s_b;
    const float4* DB = (const float4*)enc_d_b;
    const int k4 = fq;
    float4 w1 = W1[k4], w2 = W2[k4], w3 = W3[k4];
    float4 e01 = ES[2 * k4], e23 = ES[2 * k4 + 1];
    float4 d01 = ED[2 * k4], d23 = ED[2 * k4 + 1];
    float4 sb = SB[k4], db = DB[k4];
    float a0 = 0.f, a1 = 0.f, ad = 0.f, cc = 0.f, w30 = 0.f, w31 = 0.f, w3b = 0.f;
    a0 = fmaf(w1.x, e01.x, a0); a0 = fmaf(w1.y, e01.z, a0);
    a0 = fmaf(w1.z, e23.x, a0); a0 = fmaf(w1.w, e23.z, a0);
    a1 = fmaf(w1.x, e01.y, a1); a1 = fmaf(w1.y, e01.w, a1);
    a1 = fmaf(w1.z, e23.y, a1); a1 = fmaf(w1.w, e23.w, a1);
    ad = fmaf(w2.x, d01.x + d01.y, ad); ad = fmaf(w2.y, d01.z + d01.w, ad);
    ad = fmaf(w2.z, d23.x + d23.y, ad); ad = fmaf(w2.w, d23.z + d23.w, ad);
    cc = fmaf(w1.x, sb.x, cc); cc = fmaf(w1.y, sb.y, cc);
    cc = fmaf(w1.z, sb.z, cc); cc = fmaf(w1.w, sb.w, cc);
    cc = fmaf(w2.x, db.x, cc); cc = fmaf(w2.y, db.y, cc);
    cc = fmaf(w2.z, db.z, cc); cc = fmaf(w2.w, db.w, cc);
    w30 = fmaf(w3.x, e01.x, w30); w30 = fmaf(w3.y, e01.z, w30);
    w30 = fmaf(w3.z, e23.x, w30); w30 = fmaf(w3.w, e23.z, w30);
    w31 = fmaf(w3.x, e01.y, w31); w31 = fmaf(w3.y, e01.w, w31);
    w31 = fmaf(w3.z, e23.y, w31); w31 = fmaf(w3.w, e23.w, w31);
    w3b = fmaf(w3.x, sb.x, w3b); w3b = fmaf(w3.y, sb.y, w3b);
    w3b = fmaf(w3.z, sb.z, w3b); w3b = fmaf(w3.w, sb.w, w3b);
    a0  = dpp_add<0x111>(a0);  a0  = dpp_add<0x112>(a0);  a0  = dpp_add<0x114>(a0);
    a0  = dpp_add<0x118>(a0);  a0  = dpp_add<0x142>(a0);
    a1  = dpp_add<0x111>(a1);  a1  = dpp_add<0x112>(a1);  a1  = dpp_add<0x114>(a1);
    a1  = dpp_add<0x118>(a1);  a1  = dpp_add<0x142>(a1);
    ad  = dpp_add<0x111>(ad);  ad  = dpp_add<0x112>(ad);  ad  = dpp_add<0x114>(ad);
    ad  = dpp_add<0x118>(ad);  ad  = dpp_add<0x142>(ad);
    cc  = dpp_add<0x111>(cc);  cc  = dpp_add<0x112>(cc);  cc  = dpp_add<0x114>(cc);
    cc  = dpp_add<0x118>(cc);  cc  = dpp_add<0x142>(cc);
    w30 = dpp_add<0x111>(w30); w30 = dpp_add<0x112>(w30); w30 = dpp_add<0x114>(w30);
    w30 = dpp_add<0x118>(w30); w30 = dpp_add<0x142>(w30);
    w31 = dpp_add<0x111>(w31); w31 = dpp_add<0x112>(w31); w31 = dpp_add<0x114>(w31);
    w31 = dpp_add<0x118>(w31); w31 = dpp_add<0x142>(w31);
    w3b = dpp_add<0x111>(w3b); w3b = dpp_add<0x112>(w3b); w3b = dpp_add<0x114>(w3b);
    w3b = dpp_add<0x118>(w3b); w3b = dpp_add<0x142>(w3b);
    if (fq == 31) {
        ws[0 * HH + fh] = a0;
        ws[1 * HH + fh] = a1;
        ws[2 * HH + fh] = ad;
        ws[4 * HH + fh] = cc;
        ws[5 * HH + fh] = cc + w3b;
        ws[6 * HH + fh] = w30;
        ws[7 * HH + fh] = w31;
    }
    if (blockIdx.x == 0 && t < HH) ws[3 * HH + t] = v[t];
}

// 8-tanh octet, ZERO exp2 and ONE rcp: tanh(z)=z*P'(z^2)/Q'(z^2) (Pade 7/8,
// z clamped to +-5; Q'>0 so pairwise numerator/denominator combine is safe;
// normalized so oct denominator <= ~7e11, no overflow).
#define OCTET(X, ACC)                                                         \
    {                                                                         \
        v2f vx0 = {X.x, X.x}, vx1 = {X.y, X.y}, vyv = {X.z, X.z};             \
        v2f z0 = __builtin_elementwise_fma(a0_0, vx0,                         \
                 __builtin_elementwise_fma(a1_0, vx1,                         \
                 __builtin_elementwise_fma(ad_0, vyv, cg_0)));                \
        v2f z1 = __builtin_elementwise_fma(a0_1, vx0,                         \
                 __builtin_elementwise_fma(a1_1, vx1,                         \
                 __builtin_elementwise_fma(ad_1, vyv, cg_1)));                \
        v2f z2 = __builtin_elementwise_fma(a0_2, vx0,                         \
                 __builtin_elementwise_fma(a1_2, vx1,                         \
                 __builtin_elementwise_fma(ad_2, vyv, cg_2)));                \
        v2f z3 = __builtin_elementwise_fma(a0_3, vx0,                         \
                 __builtin_elementwise_fma(a1_3, vx1,                         \
                 __builtin_elementwise_fma(ad_3, vyv, cg_3)));                \
        z0 = __builtin_elementwise_min(z0, pos5);                             \
        z1 = __builtin_elementwise_min(z1, pos5);                             \
        z2 = __builtin_elementwise_min(z2, pos5);                             \
        z3 = __builtin_elementwise_min(z3, pos5);                             \
        z0 = __builtin_elementwise_max(z0, neg5);                             \
        z1 = __builtin_elementwise_max(z1, neg5);                             \
        z2 = __builtin_elementwise_max(z2, neg5);                             \
        z3 = __builtin_elementwise_max(z3, neg5);                             \
        v2f t0 = z0 * z0, t1 = z1 * z1, t2 = z2 * z2, t3 = z3 * z3;           \
        v2f p0 = __builtin_elementwise_fma(t0,                                \
                 __builtin_elementwise_fma(t0,                                \
                 __builtin_elementwise_fma(t0, pa3, pa2), pa1), onev);        \
        v2f p1 = __builtin_elementwise_fma(t1,                                \
                 __builtin_elementwise_fma(t1,                                \
                 __builtin_elementwise_fma(t1, pa3, pa2), pa1), onev);        \
        v2f p2 = __builtin_elementwise_fma(t2,                                \
                 __builtin_elementwise_fma(t2,                                \
                 __builtin_elementwise_fma(t2, pa3, pa2), pa1), onev);        \
        v2f p3 = __builtin_elementwise_fma(t3,                                \
                 __builtin_elementwise_fma(t3,                                \
                 __builtin_elementwise_fma(t3, pa3, pa2), pa1), onev);        \
        v2f q0 = __builtin_elementwise_fma(t0,                                \
                 __builtin_elementwise_fma(t0,                                \
                 __builtin_elementwise_fma(t0, qb3, qb2), qb1), onev);        \
        v2f q1 = __builtin_elementwise_fma(t1,                                \
                 __builtin_elementwise_fma(t1,                                \
                 __builtin_elementwise_fma(t1, qb3, qb2), qb1), onev);        \
        v2f q2 = __builtin_elementwise_fma(t2,                                \
                 __builtin_elementwise_fma(t2,                                \
                 __builtin_elementwise_fma(t2, qb3, qb2), qb1), onev);        \
        v2f q3 = __builtin_elementwise_fma(t3,                                \
                 __builtin_elementwise_fma(t3,                                \
                 __builtin_elementwise_fma(t3, qb3, qb2), qb1), onev);        \
        v2f nz0 = (vv_0 * z0) * p0;                                           \
        v2f nz1 = (vv_1 * z1) * p1;                                           \
        v2f nz2 = (vv_2 * z2) * p2;                                           \
        v2f nz3 = (vv_3 * z3) * p3;                                           \
        float na = fmaf(nz0.x, q0.y, nz0.y * q0.x), da = q0.x * q0.y;         \
        float nb = fmaf(nz1.x, q1.y, nz1.y * q1.x), db_ = q1.x * q1.y;        \
        float nc = fmaf(nz2.x, q2.y, nz2.y * q2.x), dc = q2.x * q2.y;         \
        float nd = fmaf(nz3.x, q3.y, nz3.y * q3.x), dd = q3.x * q3.y;         \
        float Nq0 = fmaf(na, db_, nb * da), Dq0 = da * db_;                   \
        float Nq1 = fmaf(nc, dd, nd * dc), Dq1 = dc * dd;                     \
        float Noc = fmaf(Nq0, Dq1, Nq1 * Dq0);                                \
        ACC = Noc * __builtin_amdgcn_rcpf(Dq0 * Dq1);                         \
        ACC = dpp_add<0x111>(ACC);                                            \
        ACC = dpp_add<0x112>(ACC);                                            \
        ACC = dpp_add<0x114>(ACC);                                            \
        ACC = dpp_add<0x118>(ACC);                                            \
    }

// ---- main kernel: grid B x 1024, 8 h/thread, 2 independent s per pass ----
__global__ __launch_bounds__(NT, 4) void sc_main(
    const float* __restrict__ stat, const float* __restrict__ dyn,
    const float* __restrict__ ws,
    const float* __restrict__ enc_s_w, const float* __restrict__ enc_s_b,
    const float* __restrict__ dense_w, const float* __restrict__ dense_b,
    const float* __restrict__ lin_w, const float* __restrict__ lin_b,
    float* __restrict__ out) {
    const int b    = blockIdx.x;
    const int t    = threadIdx.x;
    const int wave = t >> 6;
    const int lane = t & 63;
    const int gl   = t & 15;   // lane-in-group; h = gl*8 .. gl*8+7
    const int sg   = t >> 4;   // s-group 0..63

    __shared__ __align__(16) float4 xs[NT];
    __shared__ float4 red4[2][NW];
    __shared__ float hy_sh[HH];

    // stage per-s inputs (coalesced)
    {
        float x0 = 0.f, x1 = 0.f, yv = 0.f;
        if (t < SS) {
            const float* sbp = stat + (size_t)b * 2 * SS;
            x0 = sbp[t];
            x1 = sbp[SS + t];
            yv = dyn[(size_t)b * 2 * SS + SS + t];
        }
        xs[t] = make_float4(x0, x1, yv, 0.f);
    }

    // register-resident constants: 8 h x {a0,a1,ad,v} = 16 v2f (proven R11)
    const int h0 = gl * 8;
    float4 u, u2;
    u = *(const float4*)(ws + 0 * HH + h0); u2 = *(const float4*)(ws + 0 * HH + h0 + 4);
    const v2f a0_0 = {u.x, u.y},  a0_1 = {u.z, u.w},
              a0_2 = {u2.x, u2.y}, a0_3 = {u2.z, u2.w};
    u = *(const float4*)(ws + 1 * HH + h0); u2 = *(const float4*)(ws + 1 * HH + h0 + 4);
    const v2f a1_0 = {u.x, u.y},  a1_1 = {u.z, u.w},
              a1_2 = {u2.x, u2.y}, a1_3 = {u2.z, u2.w};
    u = *(const float4*)(ws + 2 * HH + h0); u2 = *(const float4*)(ws + 2 * HH + h0 + 4);
    const v2f ad_0 = {u.x, u.y},  ad_1 = {u.z, u.w},
              ad_2 = {u2.x, u2.y}, ad_3 = {u2.z, u2.w};
    u = *(const float4*)(ws + 3 * HH + h0); u2 = *(const float4*)(ws + 3 * HH + h0 + 4);
    const v2f vv_0 = {u.x, u.y},  vv_1 = {u.z, u.w},
              vv_2 = {u2.x, u2.y}, vv_3 = {u2.z, u2.w};
    const v2f pos5 = {5.f, 5.f}, neg5 = {-5.f, -5.f}, onev = {1.f, 1.f};
    const v2f pa1 = {PA1, PA1}, pa2 = {PA2, PA2}, pa3 = {PA3, PA3};
    const v2f qb1 = {QB1, QB1}, qb2 = {QB2, QB2}, qb3 = {QB3, QB3};
    const bool ownerBase = (gl == 15);

    __syncthreads();  // xs ready

    float X0 = 0.f, X1 = 0.f;

    for (int iter = 0; iter < 3; ++iter) {
        // per-iter bias (4 v2f)
        v2f cg_0, cg_1, cg_2, cg_3;
        if (iter == 0) {
            u = *(const float4*)(ws + 4 * HH + h0);
            u2 = *(const float4*)(ws + 4 * HH + h0 + 4);
            cg_0 = (v2f){u.x, u.y};  cg_1 = (v2f){u.z, u.w};
            cg_2 = (v2f){u2.x, u2.y}; cg_3 = (v2f){u2.z, u2.w};
        } else {
            float4 b1 = *(const float4*)(ws + 5 * HH + h0);
            float4 b2 = *(const float4*)(ws + 5 * HH + h0 + 4);
            float4 p1 = *(const float4*)(ws + 6 * HH + h0);
            float4 p2 = *(const float4*)(ws + 6 * HH + h0 + 4);
            float4 q1 = *(const float4*)(ws + 7 * HH + h0);
            float4 q2 = *(const float4*)(ws + 7 * HH + h0 + 4);
            v2f X0v = {X0, X0}, X1v = {X1, X1};
            cg_0 = __builtin_elementwise_fma(
                (v2f){p1.x, p1.y}, X0v,
                __builtin_elementwise_fma((v2f){q1.x, q1.y}, X1v, (v2f){b1.x, b1.y}));
            cg_1 = __builtin_elementwise_fma(
                (v2f){p1.z, p1.w}, X0v,
                __builtin_elementwise_fma((v2f){q1.z, q1.w}, X1v, (v2f){b1.z, b1.w}));
            cg_2 = __builtin_elementwise_fma(
                (v2f){p2.x, p2.y}, X0v,
                __builtin_elementwise_fma((v2f){q2.x, q2.y}, X1v, (v2f){b2.x, b2.y}));
            cg_3 = __builtin_elementwise_fma(
                (v2f){p2.z, p2.w}, X0v,
                __builtin_elementwise_fma((v2f){q2.z, q2.w}, X1v, (v2f){b2.z, b2.w}));
        }

        // two independent s-streams per pass (R13 structure)
        float S = 0.f, Sx0 = 0.f, Sx1 = 0.f;
        #pragma unroll 2
        for (int pass = 0; pass < 8; ++pass) {
            const int sA = pass * 64 + sg;
            const int sB = 512 + sA;
            float4 xA = xs[sA];
            float4 xB = xs[sB];
            float accA, accB;
            OCTET(xA, accA);
            OCTET(xB, accB);
            // acc (lane 15) = logit = sum_h v_h*tanh(z_h); p = exp2(C2*logit)
            float argA = ownerBase ? accA * C2 : -200.f;
            const bool ownB = ownerBase && (sB < SS);
            float argB = ownB ? accB * C2 : -200.f;
            float pA = __builtin_amdgcn_exp2f(argA);
            float pB = __builtin_amdgcn_exp2f(argB);
            S   += pA + pB;
            Sx0  = fmaf(pA, xA.x, fmaf(pB, xB.x, Sx0));
            Sx1  = fmaf(pA, xA.y, fmaf(pB, xB.y, Sx1));
        }
        // owners at lanes 15,31,47,63 (others carry exact zeros)
        S   += __shfl_xor(S, 16);   S   += __shfl_xor(S, 32);
        Sx0 += __shfl_xor(Sx0, 16); Sx0 += __shfl_xor(Sx0, 32);
        Sx1 += __shfl_xor(Sx1, 16); Sx1 += __shfl_xor(Sx1, 32);
        if (lane == 15) red4[iter & 1][wave] = make_float4(S, Sx0, Sx1, 0.f);
        __syncthreads();  // only barrier per iteration
        float4 w4 = red4[iter & 1][lane & 15];
        #pragma unroll
        for (int off = 1; off < 16; off <<= 1) {
            w4.x += __shfl_xor(w4.x, off);
            w4.y += __shfl_xor(w4.y, off);
            w4.z += __shfl_xor(w4.z, off);
        }
        float inv = __builtin_amdgcn_rcpf(w4.x);
        X0 = w4.y * inv;  // uniform across block
        X1 = w4.z * inv;
    }

    // hy[h] = enc_s_w[h,0]*X0 + enc_s_w[h,1]*X1 + enc_s_b[h]
    if (t < HH)
        hy_sh[t] = fmaf(enc_s_w[2 * t], X0, fmaf(enc_s_w[2 * t + 1], X1, enc_s_b[t]));
    __syncthreads();

    // out[b] = lin_w @ relu(dense_w @ hy + dense_b) + lin_b
    float o = 0.f;
    if (t < HH) {
        const float4* dw4 = (const float4*)(dense_w + t * HH);
        const float4* hy4 = (const float4*)hy_sh;
        float r = dense_b[t];
        #pragma unroll 4
        for (int k = 0; k < HH / 4; ++k) {
            float4 d4 = dw4[k], h4v = hy4[k];
            r = fmaf(d4.x, h4v.x, fmaf(d4.y, h4v.y, fmaf(d4.z, h4v.z, fmaf(d4.w, h4v.w, r))));
        }
        o = lin_w[t] * fmaxf(r, 0.f);
    }
    #pragma unroll
    for (int off = 32; off > 0; off >>= 1) o += __shfl_xor(o, off);
    if (lane == 0) red4[0][wave].x = o;
    __syncthreads();
    if (t == 0) {
        float s = 0.f;
        for (int i = 0; i < NW; ++i) s += red4[0][i].x;
        out[b] = s + lin_b[0];
    }
}

extern "C" void kernel_launch(void* const* d_in, const int* in_sizes, int n_in,
                              void* d_out, int out_size, void* d_ws, size_t ws_size,
                              hipStream_t stream) {
    const float* stat    = (const float*)d_in[0];
    const float* dyn     = (const float*)d_in[1];
    const float* enc_s_w = (const float*)d_in[2];
    const float* enc_s_b = (const float*)d_in[3];
    const float* enc_d_w = (const float*)d_in[4];
    const float* enc_d_b = (const float*)d_in[5];
    const float* v       = (const float*)d_in[6];
    const float* W       = (const float*)d_in[7];
    const float* dense_w = (const float*)d_in[8];
    const float* dense_b = (const float*)d_in[9];
    const float* lin_w   = (const float*)d_in[10];
    const float* lin_b   = (const float*)d_in[11];
    float* out = (float*)d_out;
    float* ws  = (float*)d_ws;

    const int B = in_sizes[0] / (2 * SS);

    hipLaunchKernelGGL(sc_fold, dim3(4), dim3(NT), 0, stream,
                       enc_s_w, enc_s_b, enc_d_w, enc_d_b, v, W, ws);
    hipLaunchKernelGGL(sc_main, dim3(B), dim3(NT), 0, stream,
                       stat, dyn, ws, enc_s_w, enc_s_b, dense_w, dense_b,
                       lin_w, lin_b, out);
}

// Round 16
// 46.914 us; speedup vs baseline: 1.3266x; 1.1141x over previous
//
#include <hip/hip_runtime.h>
#include <math.h>

#define HH  128   // hidden size
#define SS  1000  // sequence length
#define NT  1024  // threads per block (16 waves)
#define NW  (NT / 64)
#define C1 2.8853900817779268f  // 2*log2(e)
#define C2 1.4426950408889634f  // log2(e)

typedef float v2f __attribute__((ext_vector_type(2)));

// DPP adds: row_shr:N suffix-sums within 16-lane rows toward lane 15.
// Verified absmax-0 in R8/R9/R10/R11/R13.
template <int CTRL>
__device__ __forceinline__ float dpp_add(float x) {
    int s = __builtin_amdgcn_update_dpp(0, __builtin_bit_cast(int, x),
                                        CTRL, 0xF, 0xF, true);
    return x + __builtin_bit_cast(float, s);
}

// 8-sigmoid octet with ONE rcp (verified R11/R13): group-partial in ACC.
#define OCTET(X, ACC)                                                         \
    {                                                                         \
        v2f vx0 = {X.x, X.x}, vx1 = {X.y, X.y}, vyv = {X.z, X.z};             \
        v2f z0 = __builtin_elementwise_fma(a0_0, vx0,                         \
                 __builtin_elementwise_fma(a1_0, vx1,                         \
                 __builtin_elementwise_fma(ad_0, vyv, cg_0)));                \
        v2f z1 = __builtin_elementwise_fma(a0_1, vx0,                         \
                 __builtin_elementwise_fma(a1_1, vx1,                         \
                 __builtin_elementwise_fma(ad_1, vyv, cg_1)));                \
        v2f z2 = __builtin_elementwise_fma(a0_2, vx0,                         \
                 __builtin_elementwise_fma(a1_2, vx1,                         \
                 __builtin_elementwise_fma(ad_2, vyv, cg_2)));                \
        v2f z3 = __builtin_elementwise_fma(a0_3, vx0,                         \
                 __builtin_elementwise_fma(a1_3, vx1,                         \
                 __builtin_elementwise_fma(ad_3, vyv, cg_3)));                \
        z0 = __builtin_elementwise_min(z0, clampv);                           \
        z1 = __builtin_elementwise_min(z1, clampv);                           \
        z2 = __builtin_elementwise_min(z2, clampv);                           \
        z3 = __builtin_elementwise_min(z3, clampv);                           \
        float e0 = __builtin_amdgcn_exp2f(z0.x);                              \
        float e1 = __builtin_amdgcn_exp2f(z0.y);                              \
        float e2 = __builtin_amdgcn_exp2f(z1.x);                              \
        float e3 = __builtin_amdgcn_exp2f(z1.y);                              \
        float e4 = __builtin_amdgcn_exp2f(z2.x);                              \
        float e5 = __builtin_amdgcn_exp2f(z2.y);                              \
        float e6 = __builtin_amdgcn_exp2f(z3.x);                              \
        float e7 = __builtin_amdgcn_exp2f(z3.y);                              \
        float tb0 = 1.f + e1, tb1 = 1.f + e3, tb2 = 1.f + e5, tb3 = 1.f + e7; \
        float d0 = fmaf(e0, tb0, tb0);                                        \
        float d1 = fmaf(e2, tb1, tb1);                                        \
        float d2 = fmaf(e4, tb2, tb2);                                        \
        float d3 = fmaf(e6, tb3, tb3);                                        \
        float n0 = fmaf(vv_0.x, e1, fmaf(vv_0.y, e0, cp0));                   \
        float n1 = fmaf(vv_1.x, e3, fmaf(vv_1.y, e2, cp1));                   \
        float n2 = fmaf(vv_2.x, e5, fmaf(vv_2.y, e4, cp2));                   \
        float n3 = fmaf(vv_3.x, e7, fmaf(vv_3.y, e6, cp3));                   \
        float Nq0 = fmaf(n0, d1, n1 * d0), Dq0 = d0 * d1;                     \
        float Nq1 = fmaf(n2, d3, n3 * d2), Dq1 = d2 * d3;                     \
        float Noc = fmaf(Nq0, Dq1, Nq1 * Dq0);                                \
        ACC = Noc * __builtin_amdgcn_rcpf(Dq0 * Dq1);                         \
        ACC = dpp_add<0x111>(ACC);                                            \
        ACC = dpp_add<0x112>(ACC);                                            \
        ACC = dpp_add<0x114>(ACC);                                            \
        ACC = dpp_add<0x118>(ACC);                                            \
    }

// ---- single fused kernel: grid B x 1024 ----
// phase 1 = in-block DPP constant fold (R9-verified), then R13 math core.
__global__ __launch_bounds__(NT, 4) void sc_all(
    const float* __restrict__ stat, const float* __restrict__ dyn,
    const float* __restrict__ enc_s_w, const float* __restrict__ enc_s_b,
    const float* __restrict__ enc_d_w, const float* __restrict__ enc_d_b,
    const float* __restrict__ v, const float* __restrict__ W,
    const float* __restrict__ dense_w, const float* __restrict__ dense_b,
    const float* __restrict__ lin_w, const float* __restrict__ lin_b,
    float* __restrict__ out) {
    const int b    = blockIdx.x;
    const int t    = threadIdx.x;
    const int wave = t >> 6;
    const int lane = t & 63;
    const int gl   = t & 15;   // lane-in-group; h = gl*8 .. gl*8+7
    const int sg   = t >> 4;   // s-group 0..63

    __shared__ __align__(16) float4 xs[NT];    // 16 KB
    __shared__ __align__(16) float kc[8][HH];  // 4 KB folded constants
    __shared__ float4 red4[2][NW];
    __shared__ float hy_sh[HH];
    __shared__ float svc2_sh;

    // ---- phase 0: stage per-s inputs (coalesced) ----
    {
        float x0 = 0.f, x1 = 0.f, yv = 0.f;
        if (t < SS) {
            const float* sbp = stat + (size_t)b * 2 * SS;
            x0 = sbp[t];
            x1 = sbp[SS + t];
            yv = dyn[(size_t)b * 2 * SS + SS + t];
        }
        xs[t] = make_float4(x0, x1, yv, 0.f);
    }

    // ---- phase 1: in-block constant fold, split-k x 8, DPP reduce ----
    // (verbatim from R9's verified sc_fused phase 1)
    {
        const int fh = t >> 3;   // h = 0..127
        const int fq = t & 7;    // k-eighth
        const float4* W1 = (const float4*)(W + fh * (3 * HH));
        const float4* W2 = (const float4*)(W + fh * (3 * HH) + HH);
        const float4* W3 = (const float4*)(W + fh * (3 * HH) + 2 * HH);
        const float4* ES = (const float4*)enc_s_w;
        const float4* ED = (const float4*)enc_d_w;
        const float4* SB = (const float4*)enc_s_b;
        const float4* DB = (const float4*)enc_d_b;
        float a0 = 0.f, a1 = 0.f, ad = 0.f, cc = 0.f, w30 = 0.f, w31 = 0.f, w3b = 0.f;
        #pragma unroll
        for (int j = 0; j < 4; ++j) {
            const int k4 = fq * 4 + j;
            float4 w1 = W1[k4], w2 = W2[k4], w3 = W3[k4];
            float4 e01 = ES[2 * k4], e23 = ES[2 * k4 + 1];
            float4 d01 = ED[2 * k4], d23 = ED[2 * k4 + 1];
            float4 sb = SB[k4], db = DB[k4];
            a0 = fmaf(w1.x, e01.x, a0); a0 = fmaf(w1.y, e01.z, a0);
            a0 = fmaf(w1.z, e23.x, a0); a0 = fmaf(w1.w, e23.z, a0);
            a1 = fmaf(w1.x, e01.y, a1); a1 = fmaf(w1.y, e01.w, a1);
            a1 = fmaf(w1.z, e23.y, a1); a1 = fmaf(w1.w, e23.w, a1);
            ad = fmaf(w2.x, d01.x + d01.y, ad); ad = fmaf(w2.y, d01.z + d01.w, ad);
            ad = fmaf(w2.z, d23.x + d23.y, ad); ad = fmaf(w2.w, d23.z + d23.w, ad);
            cc = fmaf(w1.x, sb.x, cc); cc = fmaf(w1.y, sb.y, cc);
            cc = fmaf(w1.z, sb.z, cc); cc = fmaf(w1.w, sb.w, cc);
            cc = fmaf(w2.x, db.x, cc); cc = fmaf(w2.y, db.y, cc);
            cc = fmaf(w2.z, db.z, cc); cc = fmaf(w2.w, db.w, cc);
            w30 = fmaf(w3.x, e01.x, w30); w30 = fmaf(w3.y, e01.z, w30);
            w30 = fmaf(w3.z, e23.x, w30); w30 = fmaf(w3.w, e23.z, w30);
            w31 = fmaf(w3.x, e01.y, w31); w31 = fmaf(w3.y, e01.w, w31);
            w31 = fmaf(w3.z, e23.y, w31); w31 = fmaf(w3.w, e23.w, w31);
            w3b = fmaf(w3.x, sb.x, w3b); w3b = fmaf(w3.y, sb.y, w3b);
            w3b = fmaf(w3.z, sb.z, w3b); w3b = fmaf(w3.w, sb.w, w3b);
        }
        // 8-lane suffix reduce: lane fq==7 of each group holds the total
        a0  = dpp_add<0x111>(a0);  a0  = dpp_add<0x112>(a0);  a0  = dpp_add<0x114>(a0);
        a1  = dpp_add<0x111>(a1);  a1  = dpp_add<0x112>(a1);  a1  = dpp_add<0x114>(a1);
        ad  = dpp_add<0x111>(ad);  ad  = dpp_add<0x112>(ad);  ad  = dpp_add<0x114>(ad);
        cc  = dpp_add<0x111>(cc);  cc  = dpp_add<0x112>(cc);  cc  = dpp_add<0x114>(cc);
        w30 = dpp_add<0x111>(w30); w30 = dpp_add<0x112>(w30); w30 = dpp_add<0x114>(w30);
        w31 = dpp_add<0x111>(w31); w31 = dpp_add<0x112>(w31); w31 = dpp_add<0x114>(w31);
        w3b = dpp_add<0x111>(w3b); w3b = dpp_add<0x112>(w3b); w3b = dpp_add<0x114>(w3b);
        if (fq == 7) {
            kc[0][fh] = a0 * C1;
            kc[1][fh] = a1 * C1;
            kc[2][fh] = ad * C1;
            kc[4][fh] = cc * C1;
            kc[5][fh] = (cc + w3b) * C1;
            kc[6][fh] = w30 * C1;
            kc[7][fh] = w31 * C1;
        }
        if (t < HH) kc[3][t] = v[t];
        if (t < 32) {  // sum(v)
            float4 x = ((const float4*)v)[t];
            float s = (x.x + x.y) + (x.z + x.w);
            #pragma unroll
            for (int off = 1; off < 32; off <<= 1) s += __shfl_xor(s, off);
            if (t == 0) svc2_sh = s * C2;
        }
    }
    __syncthreads();  // xs + kc + svc2 ready

    // ---- phase 2: register-resident constants (R13 core, kc now in LDS) ----
    const int h0 = gl * 8;
    float4 u, u2;
    u = *(const float4*)&kc[0][h0]; u2 = *(const float4*)&kc[0][h0 + 4];
    const v2f a0_0 = {u.x, u.y},  a0_1 = {u.z, u.w},
              a0_2 = {u2.x, u2.y}, a0_3 = {u2.z, u2.w};
    u = *(const float4*)&kc[1][h0]; u2 = *(const float4*)&kc[1][h0 + 4];
    const v2f a1_0 = {u.x, u.y},  a1_1 = {u.z, u.w},
              a1_2 = {u2.x, u2.y}, a1_3 = {u2.z, u2.w};
    u = *(const float4*)&kc[2][h0]; u2 = *(const float4*)&kc[2][h0 + 4];
    const v2f ad_0 = {u.x, u.y},  ad_1 = {u.z, u.w},
              ad_2 = {u2.x, u2.y}, ad_3 = {u2.z, u2.w};
    u = *(const float4*)&kc[3][h0]; u2 = *(const float4*)&kc[3][h0 + 4];
    const v2f vv_0 = {u.x, u.y},  vv_1 = {u.z, u.w},
              vv_2 = {u2.x, u2.y}, vv_3 = {u2.z, u2.w};
    const float cp0 = vv_0.x + vv_0.y, cp1 = vv_1.x + vv_1.y;
    const float cp2 = vv_2.x + vv_2.y, cp3 = vv_3.x + vv_3.y;
    const float svc2 = svc2_sh;
    const v2f clampv = {14.f, 14.f};   // e<=2^14: oct denominator <= 2^112
    const bool ownerBase = (gl == 15);

    float X0 = 0.f, X1 = 0.f;

    for (int iter = 0; iter < 3; ++iter) {
        // per-iter bias (4 v2f)
        v2f cg_0, cg_1, cg_2, cg_3;
        if (iter == 0) {
            u = *(const float4*)&kc[4][h0];
            u2 = *(const float4*)&kc[4][h0 + 4];
            cg_0 = (v2f){u.x, u.y};  cg_1 = (v2f){u.z, u.w};
            cg_2 = (v2f){u2.x, u2.y}; cg_3 = (v2f){u2.z, u2.w};
        } else {
            float4 b1 = *(const float4*)&kc[5][h0];
            float4 b2 = *(const float4*)&kc[5][h0 + 4];
            float4 p1 = *(const float4*)&kc[6][h0];
            float4 p2 = *(const float4*)&kc[6][h0 + 4];
            float4 q1 = *(const float4*)&kc[7][h0];
            float4 q2 = *(const float4*)&kc[7][h0 + 4];
            v2f X0v = {X0, X0}, X1v = {X1, X1};
            cg_0 = __builtin_elementwise_fma(
                (v2f){p1.x, p1.y}, X0v,
                __builtin_elementwise_fma((v2f){q1.x, q1.y}, X1v, (v2f){b1.x, b1.y}));
            cg_1 = __builtin_elementwise_fma(
                (v2f){p1.z, p1.w}, X0v,
                __builtin_elementwise_fma((v2f){q1.z, q1.w}, X1v, (v2f){b1.z, b1.w}));
            cg_2 = __builtin_elementwise_fma(
                (v2f){p2.x, p2.y}, X0v,
                __builtin_elementwise_fma((v2f){q2.x, q2.y}, X1v, (v2f){b2.x, b2.y}));
            cg_3 = __builtin_elementwise_fma(
                (v2f){p2.z, p2.w}, X0v,
                __builtin_elementwise_fma((v2f){q2.z, q2.w}, X1v, (v2f){b2.z, b2.w}));
        }

        // two independent s-streams per pass (R13 structure, verified)
        float S = 0.f, Sx0 = 0.f, Sx1 = 0.f;
        #pragma unroll 2
        for (int pass = 0; pass < 8; ++pass) {
            const int sA = pass * 64 + sg;
            const int sB = 512 + sA;
            float4 xA = xs[sA];
            float4 xB = xs[sB];
            float accA, accB;
            OCTET(xA, accA);
            OCTET(xB, accB);
            float argA = ownerBase ? fmaf(-C1, accA, svc2) : -200.f;
            const bool ownB = ownerBase && (sB < SS);
            float argB = ownB ? fmaf(-C1, accB, svc2) : -200.f;
            float pA = __builtin_amdgcn_exp2f(argA);
            float pB = __builtin_amdgcn_exp2f(argB);
            S   += pA + pB;
            Sx0  = fmaf(pA, xA.x, fmaf(pB, xB.x, Sx0));
            Sx1  = fmaf(pA, xA.y, fmaf(pB, xB.y, Sx1));
        }
        // owners at lanes 15,31,47,63 (others carry exact zeros)
        S   += __shfl_xor(S, 16);   S   += __shfl_xor(S, 32);
        Sx0 += __shfl_xor(Sx0, 16); Sx0 += __shfl_xor(Sx0, 32);
        Sx1 += __shfl_xor(Sx1, 16); Sx1 += __shfl_xor(Sx1, 32);
        if (lane == 15) red4[iter & 1][wave] = make_float4(S, Sx0, Sx1, 0.f);
        __syncthreads();  // only barrier per iteration
        float4 w4 = red4[iter & 1][lane & 15];
        #pragma unroll
        for (int off = 1; off < 16; off <<= 1) {
            w4.x += __shfl_xor(w4.x, off);
            w4.y += __shfl_xor(w4.y, off);
            w4.z += __shfl_xor(w4.z, off);
        }
        float inv = __builtin_amdgcn_rcpf(w4.x);
        X0 = w4.y * inv;  // uniform across block
        X1 = w4.z * inv;
    }

    // hy[h] = enc_s_w[h,0]*X0 + enc_s_w[h,1]*X1 + enc_s_b[h]
    if (t < HH)
        hy_sh[t] = fmaf(enc_s_w[2 * t], X0, fmaf(enc_s_w[2 * t + 1], X1, enc_s_b[t]));
    __syncthreads();

    // out[b] = lin_w @ relu(dense_w @ hy + dense_b) + lin_b
    float o = 0.f;
    if (t < HH) {
        const float4* dw4 = (const float4*)(dense_w + t * HH);
        const float4* hy4 = (const float4*)hy_sh;
        float r = dense_b[t];
        #pragma unroll 4
        for (int k = 0; k < HH / 4; ++k) {
            float4 d4 = dw4[k], h4v = hy4[k];
            r = fmaf(d4.x, h4v.x, fmaf(d4.y, h4v.y, fmaf(d4.z, h4v.z, fmaf(d4.w, h4v.w, r))));
        }
        o = lin_w[t] * fmaxf(r, 0.f);
    }
    #pragma unroll
    for (int off = 32; off > 0; off >>= 1) o += __shfl_xor(o, off);
    if (lane == 0) red4[0][wave].x = o;
    __syncthreads();
    if (t == 0) {
        float s = 0.f;
        for (int i = 0; i < NW; ++i) s += red4[0][i].x;
        out[b] = s + lin_b[0];
    }
}

extern "C" void kernel_launch(void* const* d_in, const int* in_sizes, int n_in,
                              void* d_out, int out_size, void* d_ws, size_t ws_size,
                              hipStream_t stream) {
    const float* stat    = (const float*)d_in[0];
    const float* dyn     = (const float*)d_in[1];
    const float* enc_s_w = (const float*)d_in[2];
    const float* enc_s_b = (const float*)d_in[3];
    const float* enc_d_w = (const float*)d_in[4];
    const float* enc_d_b = (const float*)d_in[5];
    const float* v       = (const float*)d_in[6];
    const float* W       = (const float*)d_in[7];
    const float* dense_w = (const float*)d_in[8];
    const float* dense_b = (const float*)d_in[9];
    const float* lin_w   = (const float*)d_in[10];
    const float* lin_b   = (const float*)d_in[11];
    float* out = (float*)d_out;

    const int B = in_sizes[0] / (2 * SS);

    hipLaunchKernelGGL(sc_all, dim3(B), dim3(NT), 0, stream,
                       stat, dyn, enc_s_w, enc_s_b, enc_d_w, enc_d_b, v, W,
                       dense_w, dense_b, lin_w, lin_b, out);
}

// Round 17
// 40.704 us; speedup vs baseline: 1.5290x; 1.1526x over previous
//
#include <hip/hip_runtime.h>
#include <math.h>

#define HH  128   // hidden size
#define SS  1000  // sequence length
#define NT  1024  // threads per block (16 waves)
#define NW  (NT / 64)
#define C1 2.8853900817779268f  // 2*log2(e)
#define C2 1.4426950408889634f  // log2(e)

typedef float v2f __attribute__((ext_vector_type(2)));

// DPP adds: row_shr:N suffix-sums within 16-lane rows toward lane 15.
// Verified absmax-0 in R8/R10/R11/R13.
template <int CTRL>
__device__ __forceinline__ float dpp_add(float x) {
    int s = __builtin_amdgcn_update_dpp(0, __builtin_bit_cast(int, x),
                                        CTRL, 0xF, 0xF, true);
    return x + __builtin_bit_cast(float, s);
}

// ws float layout: [0..1024) kc rows 0..7 (row*128+h):
//   0:a0*C1 1:a1*C1 2:ad*C1 3:v 4:cc*C1 5:(cc+w3b)*C1 6:w30*C1 7:w31*C1
// [1024] svc2 = sum(v)*log2(e)

// ---- fold kernel: grid 4 x 1024 (verified R10/R11/R13) ----
__global__ __launch_bounds__(NT) void sc_fold(
    const float* __restrict__ enc_s_w, const float* __restrict__ enc_s_b,
    const float* __restrict__ enc_d_w, const float* __restrict__ enc_d_b,
    const float* __restrict__ v, const float* __restrict__ W,
    float* __restrict__ ws) {
    const int t  = threadIdx.x;
    const int fh = blockIdx.x * 32 + (t >> 5);
    const int fq = t & 31;
    const float4* W1 = (const float4*)(W + fh * (3 * HH));
    const float4* W2 = (const float4*)(W + fh * (3 * HH) + HH);
    const float4* W3 = (const float4*)(W + fh * (3 * HH) + 2 * HH);
    const float4* ES = (const float4*)enc_s_w;
    const float4* ED = (const float4*)enc_d_w;
    const float4* SB = (const float4*)enc_s_b;
    const float4* DB = (const float4*)enc_d_b;
    const int k4 = fq;
    float4 w1 = W1[k4], w2 = W2[k4], w3 = W3[k4];
    float4 e01 = ES[2 * k4], e23 = ES[2 * k4 + 1];
    float4 d01 = ED[2 * k4], d23 = ED[2 * k4 + 1];
    float4 sb = SB[k4], db = DB[k4];
    float a0 = 0.f, a1 = 0.f, ad = 0.f, cc = 0.f, w30 = 0.f, w31 = 0.f, w3b = 0.f;
    a0 = fmaf(w1.x, e01.x, a0); a0 = fmaf(w1.y, e01.z, a0);
    a0 = fmaf(w1.z, e23.x, a0); a0 = fmaf(w1.w, e23.z, a0);
    a1 = fmaf(w1.x, e01.y, a1); a1 = fmaf(w1.y, e01.w, a1);
    a1 = fmaf(w1.z, e23.y, a1); a1 = fmaf(w1.w, e23.w, a1);
    ad = fmaf(w2.x, d01.x + d01.y, ad); ad = fmaf(w2.y, d01.z + d01.w, ad);
    ad = fmaf(w2.z, d23.x + d23.y, ad); ad = fmaf(w2.w, d23.z + d23.w, ad);
    cc = fmaf(w1.x, sb.x, cc); cc = fmaf(w1.y, sb.y, cc);
    cc = fmaf(w1.z, sb.z, cc); cc = fmaf(w1.w, sb.w, cc);
    cc = fmaf(w2.x, db.x, cc); cc = fmaf(w2.y, db.y, cc);
    cc = fmaf(w2.z, db.z, cc); cc = fmaf(w2.w, db.w, cc);
    w30 = fmaf(w3.x, e01.x, w30); w30 = fmaf(w3.y, e01.z, w30);
    w30 = fmaf(w3.z, e23.x, w30); w30 = fmaf(w3.w, e23.z, w30);
    w31 = fmaf(w3.x, e01.y, w31); w31 = fmaf(w3.y, e01.w, w31);
    w31 = fmaf(w3.z, e23.y, w31); w31 = fmaf(w3.w, e23.w, w31);
    w3b = fmaf(w3.x, sb.x, w3b); w3b = fmaf(w3.y, sb.y, w3b);
    w3b = fmaf(w3.z, sb.z, w3b); w3b = fmaf(w3.w, sb.w, w3b);
    a0  = dpp_add<0x111>(a0);  a0  = dpp_add<0x112>(a0);  a0  = dpp_add<0x114>(a0);
    a0  = dpp_add<0x118>(a0);  a0  = dpp_add<0x142>(a0);
    a1  = dpp_add<0x111>(a1);  a1  = dpp_add<0x112>(a1);  a1  = dpp_add<0x114>(a1);
    a1  = dpp_add<0x118>(a1);  a1  = dpp_add<0x142>(a1);
    ad  = dpp_add<0x111>(ad);  ad  = dpp_add<0x112>(ad);  ad  = dpp_add<0x114>(ad);
    ad  = dpp_add<0x118>(ad);  ad  = dpp_add<0x142>(ad);
    cc  = dpp_add<0x111>(cc);  cc  = dpp_add<0x112>(cc);  cc  = dpp_add<0x114>(cc);
    cc  = dpp_add<0x118>(cc);  cc  = dpp_add<0x142>(cc);
    w30 = dpp_add<0x111>(w30); w30 = dpp_add<0x112>(w30); w30 = dpp_add<0x114>(w30);
    w30 = dpp_add<0x118>(w30); w30 = dpp_add<0x142>(w30);
    w31 = dpp_add<0x111>(w31); w31 = dpp_add<0x112>(w31); w31 = dpp_add<0x114>(w31);
    w31 = dpp_add<0x118>(w31); w31 = dpp_add<0x142>(w31);
    w3b = dpp_add<0x111>(w3b); w3b = dpp_add<0x112>(w3b); w3b = dpp_add<0x114>(w3b);
    w3b = dpp_add<0x118>(w3b); w3b = dpp_add<0x142>(w3b);
    if (fq == 31) {
        ws[0 * HH + fh] = a0 * C1;
        ws[1 * HH + fh] = a1 * C1;
        ws[2 * HH + fh] = ad * C1;
        ws[4 * HH + fh] = cc * C1;
        ws[5 * HH + fh] = (cc + w3b) * C1;
        ws[6 * HH + fh] = w30 * C1;
        ws[7 * HH + fh] = w31 * C1;
    }
    if (blockIdx.x == 0) {
        if (t < HH) ws[3 * HH + t] = v[t];
        if (t < 32) {
            float4 x = ((const float4*)v)[t];
            float s = (x.x + x.y) + (x.z + x.w);
            #pragma unroll
            for (int off = 1; off < 32; off <<= 1) s += __shfl_xor(s, off);
            if (t == 0) ws[8 * HH] = s * C2;
        }
    }
}

// 8-sigmoid octet with ONE rcp (verified R11): returns group-partial acc.
#define OCTET(X, ACC)                                                         \
    {                                                                         \
        v2f vx0 = {X.x, X.x}, vx1 = {X.y, X.y}, vyv = {X.z, X.z};             \
        v2f z0 = __builtin_elementwise_fma(a0_0, vx0,                         \
                 __builtin_elementwise_fma(a1_0, vx1,                         \
                 __builtin_elementwise_fma(ad_0, vyv, cg_0)));                \
        v2f z1 = __builtin_elementwise_fma(a0_1, vx0,                         \
                 __builtin_elementwise_fma(a1_1, vx1,                         \
                 __builtin_elementwise_fma(ad_1, vyv, cg_1)));                \
        v2f z2 = __builtin_elementwise_fma(a0_2, vx0,                         \
                 __builtin_elementwise_fma(a1_2, vx1,                         \
                 __builtin_elementwise_fma(ad_2, vyv, cg_2)));                \
        v2f z3 = __builtin_elementwise_fma(a0_3, vx0,                         \
                 __builtin_elementwise_fma(a1_3, vx1,                         \
                 __builtin_elementwise_fma(ad_3, vyv, cg_3)));                \
        z0 = __builtin_elementwise_min(z0, clampv);                           \
        z1 = __builtin_elementwise_min(z1, clampv);                           \
        z2 = __builtin_elementwise_min(z2, clampv);                           \
        z3 = __builtin_elementwise_min(z3, clampv);                           \
        float e0 = __builtin_amdgcn_exp2f(z0.x);                              \
        float e1 = __builtin_amdgcn_exp2f(z0.y);                              \
        float e2 = __builtin_amdgcn_exp2f(z1.x);                              \
        float e3 = __builtin_amdgcn_exp2f(z1.y);                              \
        float e4 = __builtin_amdgcn_exp2f(z2.x);                              \
        float e5 = __builtin_amdgcn_exp2f(z2.y);                              \
        float e6 = __builtin_amdgcn_exp2f(z3.x);                              \
        float e7 = __builtin_amdgcn_exp2f(z3.y);                              \
        float tb0 = 1.f + e1, tb1 = 1.f + e3, tb2 = 1.f + e5, tb3 = 1.f + e7; \
        float d0 = fmaf(e0, tb0, tb0);                                        \
        float d1 = fmaf(e2, tb1, tb1);                                        \
        float d2 = fmaf(e4, tb2, tb2);                                        \
        float d3 = fmaf(e6, tb3, tb3);                                        \
        float n0 = fmaf(vv_0.x, e1, fmaf(vv_0.y, e0, cp0));                   \
        float n1 = fmaf(vv_1.x, e3, fmaf(vv_1.y, e2, cp1));                   \
        float n2 = fmaf(vv_2.x, e5, fmaf(vv_2.y, e4, cp2));                   \
        float n3 = fmaf(vv_3.x, e7, fmaf(vv_3.y, e6, cp3));                   \
        float Nq0 = fmaf(n0, d1, n1 * d0), Dq0 = d0 * d1;                     \
        float Nq1 = fmaf(n2, d3, n3 * d2), Dq1 = d2 * d3;                     \
        float Noc = fmaf(Nq0, Dq1, Nq1 * Dq0);                                \
        ACC = Noc * __builtin_amdgcn_rcpf(Dq0 * Dq1);                         \
        ACC = dpp_add<0x111>(ACC);                                            \
        ACC = dpp_add<0x112>(ACC);                                            \
        ACC = dpp_add<0x114>(ACC);                                            \
        ACC = dpp_add<0x118>(ACC);                                            \
    }

// ---- main kernel: grid B x 1024, 8 h/thread, 2 independent s per pass ----
__global__ __launch_bounds__(NT, 4) void sc_main(
    const float* __restrict__ stat, const float* __restrict__ dyn,
    const float* __restrict__ ws,
    const float* __restrict__ enc_s_w, const float* __restrict__ enc_s_b,
    const float* __restrict__ dense_w, const float* __restrict__ dense_b,
    const float* __restrict__ lin_w, const float* __restrict__ lin_b,
    float* __restrict__ out) {
    const int b    = blockIdx.x;
    const int t    = threadIdx.x;
    const int wave = t >> 6;
    const int lane = t & 63;
    const int gl   = t & 15;   // lane-in-group; h = gl*8 .. gl*8+7
    const int sg   = t >> 4;   // s-group 0..63

    __shared__ __align__(16) float4 xs[NT];
    __shared__ float4 red4[2][NW];
    __shared__ float hy_sh[HH];

    // stage per-s inputs (coalesced)
    {
        float x0 = 0.f, x1 = 0.f, yv = 0.f;
        if (t < SS) {
            const float* sbp = stat + (size_t)b * 2 * SS;
            x0 = sbp[t];
            x1 = sbp[SS + t];
            yv = dyn[(size_t)b * 2 * SS + SS + t];
        }
        xs[t] = make_float4(x0, x1, yv, 0.f);
    }

    // register-resident constants: 8 h x {a0,a1,ad,v} = 16 v2f (proven R11)
    const int h0 = gl * 8;
    float4 u, u2;
    u = *(const float4*)(ws + 0 * HH + h0); u2 = *(const float4*)(ws + 0 * HH + h0 + 4);
    const v2f a0_0 = {u.x, u.y},  a0_1 = {u.z, u.w},
              a0_2 = {u2.x, u2.y}, a0_3 = {u2.z, u2.w};
    u = *(const float4*)(ws + 1 * HH + h0); u2 = *(const float4*)(ws + 1 * HH + h0 + 4);
    const v2f a1_0 = {u.x, u.y},  a1_1 = {u.z, u.w},
              a1_2 = {u2.x, u2.y}, a1_3 = {u2.z, u2.w};
    u = *(const float4*)(ws + 2 * HH + h0); u2 = *(const float4*)(ws + 2 * HH + h0 + 4);
    const v2f ad_0 = {u.x, u.y},  ad_1 = {u.z, u.w},
              ad_2 = {u2.x, u2.y}, ad_3 = {u2.z, u2.w};
    u = *(const float4*)(ws + 3 * HH + h0); u2 = *(const float4*)(ws + 3 * HH + h0 + 4);
    const v2f vv_0 = {u.x, u.y},  vv_1 = {u.z, u.w},
              vv_2 = {u2.x, u2.y}, vv_3 = {u2.z, u2.w};
    const float cp0 = vv_0.x + vv_0.y, cp1 = vv_1.x + vv_1.y;
    const float cp2 = vv_2.x + vv_2.y, cp3 = vv_3.x + vv_3.y;
    const float svc2 = ws[8 * HH];
    const v2f clampv = {14.f, 14.f};   // e<=2^14: oct denominator <= 2^112
    const bool ownerBase = (gl == 15);

    __syncthreads();  // xs ready

    float X0 = 0.f, X1 = 0.f;

    for (int iter = 0; iter < 3; ++iter) {
        // per-iter bias (4 v2f)
        v2f cg_0, cg_1, cg_2, cg_3;
        if (iter == 0) {
            u = *(const float4*)(ws + 4 * HH + h0);
            u2 = *(const float4*)(ws + 4 * HH + h0 + 4);
            cg_0 = (v2f){u.x, u.y};  cg_1 = (v2f){u.z, u.w};
            cg_2 = (v2f){u2.x, u2.y}; cg_3 = (v2f){u2.z, u2.w};
        } else {
            float4 b1 = *(const float4*)(ws + 5 * HH + h0);
            float4 b2 = *(const float4*)(ws + 5 * HH + h0 + 4);
            float4 p1 = *(const float4*)(ws + 6 * HH + h0);
            float4 p2 = *(const float4*)(ws + 6 * HH + h0 + 4);
            float4 q1 = *(const float4*)(ws + 7 * HH + h0);
            float4 q2 = *(const float4*)(ws + 7 * HH + h0 + 4);
            v2f X0v = {X0, X0}, X1v = {X1, X1};
            cg_0 = __builtin_elementwise_fma(
                (v2f){p1.x, p1.y}, X0v,
                __builtin_elementwise_fma((v2f){q1.x, q1.y}, X1v, (v2f){b1.x, b1.y}));
            cg_1 = __builtin_elementwise_fma(
                (v2f){p1.z, p1.w}, X0v,
                __builtin_elementwise_fma((v2f){q1.z, q1.w}, X1v, (v2f){b1.z, b1.w}));
            cg_2 = __builtin_elementwise_fma(
                (v2f){p2.x, p2.y}, X0v,
                __builtin_elementwise_fma((v2f){q2.x, q2.y}, X1v, (v2f){b2.x, b2.y}));
            cg_3 = __builtin_elementwise_fma(
                (v2f){p2.z, p2.w}, X0v,
                __builtin_elementwise_fma((v2f){q2.z, q2.w}, X1v, (v2f){b2.z, b2.w}));
        }

        // two independent s-streams per pass: sA = pass*64+sg (always < 512,
        // valid), sB = 512 + pass*64+sg (valid iff < SS)
        float S = 0.f, Sx0 = 0.f, Sx1 = 0.f;
        #pragma unroll 2
        for (int pass = 0; pass < 8; ++pass) {
            const int sA = pass * 64 + sg;
            const int sB = 512 + sA;
            float4 xA = xs[sA];
            float4 xB = xs[sB];
            float accA, accB;
            OCTET(xA, accA);
            OCTET(xB, accB);
            float argA = ownerBase ? fmaf(-C1, accA, svc2) : -200.f;
            const bool ownB = ownerBase && (sB < SS);
            float argB = ownB ? fmaf(-C1, accB, svc2) : -200.f;
            float pA = __builtin_amdgcn_exp2f(argA);
            float pB = __builtin_amdgcn_exp2f(argB);
            S   += pA + pB;
            Sx0  = fmaf(pA, xA.x, fmaf(pB, xB.x, Sx0));
            Sx1  = fmaf(pA, xA.y, fmaf(pB, xB.y, Sx1));
        }
        // owners at lanes 15,31,47,63 (others carry exact zeros)
        S   += __shfl_xor(S, 16);   S   += __shfl_xor(S, 32);
        Sx0 += __shfl_xor(Sx0, 16); Sx0 += __shfl_xor(Sx0, 32);
        Sx1 += __shfl_xor(Sx1, 16); Sx1 += __shfl_xor(Sx1, 32);
        if (lane == 15) red4[iter & 1][wave] = make_float4(S, Sx0, Sx1, 0.f);
        __syncthreads();  // only barrier per iteration
        float4 w4 = red4[iter & 1][lane & 15];
        #pragma unroll
        for (int off = 1; off < 16; off <<= 1) {
            w4.x += __shfl_xor(w4.x, off);
            w4.y += __shfl_xor(w4.y, off);
            w4.z += __shfl_xor(w4.z, off);
        }
        float inv = __builtin_amdgcn_rcpf(w4.x);
        X0 = w4.y * inv;  // uniform across block
        X1 = w4.z * inv;
    }

    // hy[h] = enc_s_w[h,0]*X0 + enc_s_w[h,1]*X1 + enc_s_b[h]
    if (t < HH)
        hy_sh[t] = fmaf(enc_s_w[2 * t], X0, fmaf(enc_s_w[2 * t + 1], X1, enc_s_b[t]));
    __syncthreads();

    // out[b] = lin_w @ relu(dense_w @ hy + dense_b) + lin_b
    float o = 0.f;
    if (t < HH) {
        const float4* dw4 = (const float4*)(dense_w + t * HH);
        const float4* hy4 = (const float4*)hy_sh;
        float r = dense_b[t];
        #pragma unroll 4
        for (int k = 0; k < HH / 4; ++k) {
            float4 d4 = dw4[k], h4v = hy4[k];
            r = fmaf(d4.x, h4v.x, fmaf(d4.y, h4v.y, fmaf(d4.z, h4v.z, fmaf(d4.w, h4v.w, r))));
        }
        o = lin_w[t] * fmaxf(r, 0.f);
    }
    #pragma unroll
    for (int off = 32; off > 0; off >>= 1) o += __shfl_xor(o, off);
    if (lane == 0) red4[0][wave].x = o;
    __syncthreads();
    if (t == 0) {
        float s = 0.f;
        for (int i = 0; i < NW; ++i) s += red4[0][i].x;
        out[b] = s + lin_b[0];
    }
}

extern "C" void kernel_launch(void* const* d_in, const int* in_sizes, int n_in,
                              void* d_out, int out_size, void* d_ws, size_t ws_size,
                              hipStream_t stream) {
    const float* stat    = (const float*)d_in[0];
    const float* dyn     = (const float*)d_in[1];
    const float* enc_s_w = (const float*)d_in[2];
    const float* enc_s_b = (const float*)d_in[3];
    const float* enc_d_w = (const float*)d_in[4];
    const float* enc_d_b = (const float*)d_in[5];
    const float* v       = (const float*)d_in[6];
    const float* W       = (const float*)d_in[7];
    const float* dense_w = (const float*)d_in[8];
    const float* dense_b = (const float*)d_in[9];
    const float* lin_w   = (const float*)d_in[10];
    const float* lin_b   = (const float*)d_in[11];
    float* out = (float*)d_out;
    float* ws  = (float*)d_ws;

    const int B = in_sizes[0] / (2 * SS);

    hipLaunchKernelGGL(sc_fold, dim3(4), dim3(NT), 0, stream,
                       enc_s_w, enc_s_b, enc_d_w, enc_d_b, v, W, ws);
    hipLaunchKernelGGL(sc_main, dim3(B), dim3(NT), 0, stream,
                       stat, dyn, ws, enc_s_w, enc_s_b, dense_w, dense_b,
                       lin_w, lin_b, out);
}